// Round 3
// baseline (1038.941 us; speedup 1.0000x reference)
//
#include <hip/hip_runtime.h>
#include <math.h>
#include <string.h>

#define TILE    32
#define HALO    9
#define IN_T    (TILE + 2*HALO)     /* 50 */
#define IMG_H   512
#define IMG_W   512
#define NPIX    (IMG_H*IMG_W)       /* 262144 = 1<<18 */
#define NIMG    16
#define NSIG    5
#define MAXL    19
#define MIN_SZ  200
#define TSTRIDE 51                  /* padded LDS stride for t-arrays */

struct Taps {
  float k[NSIG][3][MAXL];
  float s2[NSIG];
  int   rad[NSIG];
};

// ---------------------------------------------------------------------------
// Frangi per-sigma. Weights indexed with compile-time constants -> s_load ->
// SGPR (zero VALU/LDS cost). Conv convention (== reference _corr1d):
//   y[i] = sum_j x[i + j - RAD] * k[L-1-j].
//
// Pass 1 (vertical, read-driven): thread -> (t-col c, 8-row group g).
//   Walks L+7 input rows down the column; each LDS read (immediate offset)
//   feeds up to 24 FMAs (8 rows x 3 kernels). One slot/thread, no slot loop.
// Pass 2 (horizontal): thread -> (row, 4 consecutive cols), circular window
//   with compile-time rotation; then eigenvalues + vesselness.
// ---------------------------------------------------------------------------
template<int SIG, int RAD>
__device__ __forceinline__ void do_sigma(const float* __restrict__ sIn,
                                         float* __restrict__ t0,
                                         float* __restrict__ t1,
                                         float* __restrict__ t2,
                                         const Taps& taps, int tid, float* fr)
{
  constexpr int L  = 2*RAD + 1;
  constexpr int WV = TILE + 2*RAD;       // t-array cols (with horizontal halo)

  // ---- pass 1: vertical conv of sIn -> t0(k0), t1(k1), t2(k2) ----
  {
    int c = tid >> 2;                    // t col
    int g = tid & 3;                     // row group (8 rows each)
    if (c < WV) {
      int base = (g*8 + HALO - RAD)*IN_T + (c + HALO - RAD);
      float a0[8] = {0,0,0,0,0,0,0,0};
      float a1[8] = {0,0,0,0,0,0,0,0};
      float a2[8] = {0,0,0,0,0,0,0,0};
#pragma unroll
      for (int m = 0; m < L+7; ++m) {    // input row (rel. to base)
        float x = sIn[base + m*IN_T];
#pragma unroll
        for (int i = 0; i < 8; ++i) {    // output row in group
          if (i <= m && m - i <= L-1) {  // tap j = m-i in [0,L)
            a0[i] += x * taps.k[SIG][0][L-1-(m-i)];
            a1[i] += x * taps.k[SIG][1][L-1-(m-i)];
            a2[i] += x * taps.k[SIG][2][L-1-(m-i)];
          }
        }
      }
      int tb = g*8*TSTRIDE + c;
#pragma unroll
      for (int i = 0; i < 8; ++i) {
        t0[tb + i*TSTRIDE] = a0[i];
        t1[tb + i*TSTRIDE] = a1[i];
        t2[tb + i*TSTRIDE] = a2[i];
      }
    }
  }
  __syncthreads();

  // ---- pass 2: horizontal conv + vesselness ----
  {
    int r    = tid >> 3;
    int c0   = (tid & 7) * 4;
    int base = r*TSTRIDE + c0;
    float hrr[4] = {0,0,0,0}, hrc[4] = {0,0,0,0}, hcc[4] = {0,0,0,0};
    float u0[4], u1[4], u2[4];           // circular window, col c0+m at slot m&3
#pragma unroll
    for (int k = 0; k < 4; ++k) { u0[k] = t0[base+k]; u1[k] = t1[base+k]; u2[k] = t2[base+k]; }
#pragma unroll
    for (int j = 0; j < L; ++j) {
      float w0 = taps.k[SIG][0][L-1-j];
      float w1 = taps.k[SIG][1][L-1-j];
      float w2 = taps.k[SIG][2][L-1-j];
#pragma unroll
      for (int k = 0; k < 4; ++k) {
        hrr[k] += u2[(j+k)&3]*w0;        // Hrr = vert k2 (.) horiz k0
        hrc[k] += u1[(j+k)&3]*w1;        // Hrc = vert k1 (.) horiz k1
        hcc[k] += u0[(j+k)&3]*w2;        // Hcc = vert k0 (.) horiz k2
      }
      if (j < L-1) {
        u0[j&3] = t0[base + j + 4];
        u1[j&3] = t1[base + j + 4];
        u2[j&3] = t2[base + j + 4];
      }
    }
    float s2 = taps.s2[SIG];
#pragma unroll
    for (int k = 0; k < 4; ++k) {
      float Hrr = hrr[k]*s2, Hrc = hrc[k]*s2, Hcc = hcc[k]*s2;
      float mid  = 0.5f*(Hrr + Hcc);
      float dif  = 0.5f*(Hrr - Hcc);
      float disc = sqrtf(dif*dif + Hrc*Hrc);
      float ehi  = mid + disc;
      float elo  = mid - disc;
      bool  sm   = fabsf(ehi) <= fabsf(elo);
      float lam1 = sm ? ehi : elo;
      float lam2 = sm ? elo : ehi;
      float lam2c = fmaxf(lam2, 1e-10f);
      float q    = lam1 / lam2c;
      float rb2  = q*q;
      float ssq  = lam1*lam1 + lam2*lam2;
      float v    = expf((-rb2)/2.0f) * (1.0f - expf((-ssq)/50.0f));
      fr[k] = fmaxf(fr[k], v);
    }
  }
  __syncthreads();                       // t-arrays free for next sigma
}

__global__ __launch_bounds__(256, 4)
void frangi_label_kernel(const float* __restrict__ img,
                         int* __restrict__ labels,
                         int* __restrict__ sizes,
                         Taps taps)
{
  __shared__ float sIn[IN_T*IN_T];
  __shared__ float t0[TILE*TSTRIDE];
  __shared__ float t1[TILE*TSTRIDE];
  __shared__ float t2[TILE*TSTRIDE];

  const int tid    = threadIdx.x;
  const int imgIdx = blockIdx.y;
  const int tIdx   = blockIdx.x;
  const int tr0    = (tIdx >> 4) * TILE;
  const int tc0    = (tIdx & 15) * TILE;
  const float* __restrict__ im = img + (size_t)imgIdx * NPIX;

  // load halo tile: reflect ('symmetric') padding, negate+scale: -(x*500)
  for (int i = tid; i < IN_T*IN_T; i += 256) {
    int r = i / IN_T;
    int c = i - r*IN_T;
    int gr = tr0 - HALO + r;
    int gc = tc0 - HALO + c;
    gr = (gr < 0) ? (-1 - gr) : ((gr >= IMG_H) ? (2*IMG_H - 1 - gr) : gr);
    gc = (gc < 0) ? (-1 - gc) : ((gc >= IMG_W) ? (2*IMG_W - 1 - gc) : gc);
    sIn[i] = -(im[gr*IMG_W + gc] * 500.0f);
  }
  __syncthreads();

  float fr[4] = {0.0f, 0.0f, 0.0f, 0.0f};
  do_sigma<0,4>(sIn, t0, t1, t2, taps, tid, fr);   // sigma 1.0
  do_sigma<1,5>(sIn, t0, t1, t2, taps, tid, fr);   // sigma 1.3
  do_sigma<2,6>(sIn, t0, t1, t2, taps, tid, fr);   // sigma 1.6
  do_sigma<3,8>(sIn, t0, t1, t2, taps, tid, fr);   // sigma 1.9
  do_sigma<4,9>(sIn, t0, t1, t2, taps, tid, fr);   // sigma 2.2

  const int r  = tid >> 3;
  const int c0 = (tid & 7) * 4;
  const int gr = tr0 + r;
  const size_t imgBase = (size_t)imgIdx * NPIX;
#pragma unroll
  for (int k = 0; k < 4; ++k) {
    int p = gr*IMG_W + tc0 + c0 + k;
    float x = im[p];
    bool m = (x >= 0.1f) && (x <= 0.5f) && (fr[k] >= 0.2f);
    labels[imgBase + p] = m ? p : -1;
    sizes[imgBase + p]  = 0;
  }
}

// ---------------------------------------------------------------------------
// 8-connected CCL: atomic union-find (min-index root), then size filter.
// ---------------------------------------------------------------------------
__device__ __forceinline__ int ldA(const int* p) {
  return __hip_atomic_load(p, __ATOMIC_RELAXED, __HIP_MEMORY_SCOPE_AGENT);
}
__device__ __forceinline__ int rootOf(const int* L, int x) {
  int pa = ldA(&L[x]);
  while (pa != x) { int g = ldA(&L[pa]); x = pa; pa = g; }
  return x;
}

__global__ __launch_bounds__(256)
void merge_kernel(int* __restrict__ labels)
{
  int gid = blockIdx.x*256 + threadIdx.x;
  int img = gid >> 18;
  int p   = gid & (NPIX - 1);
  int* L  = labels + ((size_t)img << 18);
  if (L[p] < 0) return;
  int r = p >> 9, c = p & (IMG_W - 1);
  const int dr[4] = {0,-1,-1,-1};
  const int dc[4] = {-1,-1,0,1};
#pragma unroll
  for (int k = 0; k < 4; ++k) {
    int nr = r + dr[k], nc = c + dc[k];
    if (nr < 0 || nc < 0 || nc >= IMG_W) continue;
    int q = (nr << 9) | nc;
    if (L[q] < 0) continue;
    int a = p, b = q;
    while (true) {
      a = rootOf(L, a);
      b = rootOf(L, b);
      if (a == b) break;
      int hi = a > b ? a : b;
      int lo = a < b ? a : b;
      int old = atomicCAS(&L[hi], hi, lo);     // link high root under low root
      if (old == hi) break;
      a = old; b = lo;
    }
  }
}

// compress to root + run-length-aggregated size count, fused.
__global__ __launch_bounds__(256)
void compress_count_kernel(int* __restrict__ labels, int* __restrict__ sizes)
{
  int gid = blockIdx.x*256 + threadIdx.x;
  int img = gid >> 18;
  int p   = gid & (NPIX - 1);
  int* L  = labels + ((size_t)img << 18);
  int rt  = -1;
  if (ldA(&L[p]) >= 0) {
    rt = rootOf(L, p);
    __hip_atomic_store(&L[p], rt, __ATOMIC_RELAXED, __HIP_MEMORY_SCOPE_AGENT);
  }
  int lane = threadIdx.x & 63;
  int left = __shfl_up(rt, 1);
  bool head = (lane == 0) || (left != rt);
  unsigned long long hb = __ballot(head);
  if (rt >= 0 && head) {
    unsigned long long rest = (hb >> 1) >> lane;   // heads strictly above
    int len = rest ? __ffsll((long long)rest) : (64 - lane);
    atomicAdd(&sizes[((size_t)img << 18) + rt], len);
  }
}

__global__ __launch_bounds__(256)
void output_kernel(const int* __restrict__ labels, const int* __restrict__ sizes,
                   float* __restrict__ out)
{
  int gid = blockIdx.x*256 + threadIdx.x;
  int l = labels[gid];
  float v = 0.0f;
  if (l >= 0) {
    int img = gid >> 18;
    v = (sizes[((size_t)img << 18) + l] >= MIN_SZ) ? 1.0f : 0.0f;
  }
  out[gid] = v;
}

// ---------------------------------------------------------------------------
// Host: scipy.ndimage-style Gaussian derivative kernels (truncate=4), double
// precision exactly as numpy computes them, cast to f32.
// ---------------------------------------------------------------------------
static void gauss1d(double sigma, int order, int rad, float* out)
{
  int L = 2*rad + 1;
  double phi[MAXL];
  double s = 0.0;
  for (int i = 0; i < L; ++i) {
    double x = (double)(i - rad);
    phi[i] = exp(-0.5*x*x/(sigma*sigma));
    s += phi[i];
  }
  for (int i = 0; i < L; ++i) phi[i] /= s;
  if (order == 0) {
    for (int i = 0; i < L; ++i) out[i] = (float)phi[i];
    return;
  }
  double q[3] = {1.0, 0.0, 0.0};
  for (int it = 0; it < order; ++it) {
    double nq[3] = {0.0, 0.0, 0.0};
    for (int i = 0; i <= order; ++i) {
      double v = 0.0;
      if (i+1 <= order) v += (double)(i+1) * q[i+1];
      if (i-1 >= 0)     v += (-1.0/(sigma*sigma)) * q[i-1];
      nq[i] = v;
    }
    q[0] = nq[0]; q[1] = nq[1]; q[2] = nq[2];
  }
  for (int i = 0; i < L; ++i) {
    double x = (double)(i - rad);
    double poly = q[0];
    double xp = x;
    for (int e = 1; e <= order; ++e) { poly += xp*q[e]; xp *= x; }
    out[i] = (float)(poly*phi[i]);
  }
}

extern "C" void kernel_launch(void* const* d_in, const int* in_sizes, int n_in,
                              void* d_out, int out_size, void* d_ws, size_t ws_size,
                              hipStream_t stream)
{
  (void)in_sizes; (void)n_in; (void)out_size; (void)ws_size;
  const float* img = (const float*)d_in[0];
  float* out = (float*)d_out;
  int* labels = (int*)d_ws;
  int* sizes  = labels + (size_t)NIMG * NPIX;

  Taps taps;
  memset(&taps, 0, sizeof(taps));
  for (int s = 0; s < NSIG; ++s) {
    double sigma = 1.0 + 0.3 * (double)s;      // np.arange(1.0, 2.5, 0.3)
    int rad = (int)(4.0 * sigma + 0.5);        // 4,5,6,8,9
    taps.rad[s] = rad;
    taps.s2[s]  = (float)(sigma * sigma);
    for (int o = 0; o < 3; ++o) gauss1d(sigma, o, rad, taps.k[s][o]);
  }

  dim3 gridF(NPIX / (TILE*TILE), NIMG);        // 256 tiles x 16 images
  frangi_label_kernel<<<gridF, 256, 0, stream>>>(img, labels, sizes, taps);

  int blocks = (NIMG * NPIX) / 256;            // 16384
  merge_kernel         <<<blocks, 256, 0, stream>>>(labels);
  compress_count_kernel<<<blocks, 256, 0, stream>>>(labels, sizes);
  output_kernel        <<<blocks, 256, 0, stream>>>(labels, sizes, out);
}

// Round 4
// 444.018 us; speedup vs baseline: 2.3399x; 2.3399x over previous
//
#include <hip/hip_runtime.h>
#include <math.h>
#include <string.h>

#define TILE    32
#define HALO    9
#define IN_T    (TILE + 2*HALO)     /* 50 */
#define IMG_H   512
#define IMG_W   512
#define NPIX    (IMG_H*IMG_W)       /* 262144 = 1<<18 */
#define NIMG    16
#define NSIG    5
#define MAXL    19
#define MIN_SZ  200
#define TSTRIDE 51                  /* padded LDS stride for t-arrays */

struct Taps {
  float k[NSIG][3][MAXL];
  float s2[NSIG];
  int   rad[NSIG];
};

// ---------------------------------------------------------------------------
// Frangi per-sigma. Weights indexed with compile-time constants -> s_load ->
// SGPR. Conv convention (== reference _corr1d):
//   y[i] = sum_j x[i + j - RAD] * k[L-1-j].
//
// Pass 1 (vertical, tap-driven): thread -> (t-col c, 8-row group g).
//   Circular 8-deep x-window in registers; per tap j: 1 LDS read + 24 FMA
//   (8 rows x 3 kernels) with compile-time window slots and SGPR weights.
//   Live state ~ 8 window + 24 acc regs.
// Pass 2 (horizontal): thread -> (row, 4 consecutive cols), circular window
//   with compile-time rotation; then eigenvalues + vesselness.
// ---------------------------------------------------------------------------
template<int SIG, int RAD>
__device__ __forceinline__ void do_sigma(const float* __restrict__ sIn,
                                         float* __restrict__ t0,
                                         float* __restrict__ t1,
                                         float* __restrict__ t2,
                                         const Taps& taps, int tid, float* fr)
{
  constexpr int L  = 2*RAD + 1;
  constexpr int WV = TILE + 2*RAD;       // t-array cols (with horizontal halo)

  // ---- pass 1: vertical conv of sIn -> t0(k0), t1(k1), t2(k2) ----
  {
    int c = tid >> 2;                    // t col
    int g = tid & 3;                     // 8-row group
    if (c < WV) {
      int base = (g*8 + HALO - RAD)*IN_T + (c + HALO - RAD);
      float w[8];                        // circular window: x[j..j+7]
#pragma unroll
      for (int m = 0; m < 7; ++m) w[m] = sIn[base + m*IN_T];
      float a0[8] = {0,0,0,0,0,0,0,0};
      float a1[8] = {0,0,0,0,0,0,0,0};
      float a2[8] = {0,0,0,0,0,0,0,0};
#pragma unroll
      for (int j = 0; j < L; ++j) {
        w[(j+7)&7] = sIn[base + (j+7)*IN_T];   // x[j+7] replaces x[j-1]
        float k0 = taps.k[SIG][0][L-1-j];
        float k1 = taps.k[SIG][1][L-1-j];
        float k2 = taps.k[SIG][2][L-1-j];
#pragma unroll
        for (int i = 0; i < 8; ++i) {          // output row g*8+i uses x[i+j]
          float x = w[(j+i)&7];
          a0[i] += x*k0;
          a1[i] += x*k1;
          a2[i] += x*k2;
        }
      }
      int tb = g*8*TSTRIDE + c;
#pragma unroll
      for (int i = 0; i < 8; ++i) {
        t0[tb + i*TSTRIDE] = a0[i];
        t1[tb + i*TSTRIDE] = a1[i];
        t2[tb + i*TSTRIDE] = a2[i];
      }
    }
  }
  __syncthreads();

  // ---- pass 2: horizontal conv + vesselness ----
  {
    int r    = tid >> 3;
    int c0   = (tid & 7) * 4;
    int base = r*TSTRIDE + c0;
    float hrr[4] = {0,0,0,0}, hrc[4] = {0,0,0,0}, hcc[4] = {0,0,0,0};
    float u0[4], u1[4], u2[4];           // circular window, col c0+m at slot m&3
#pragma unroll
    for (int k = 0; k < 4; ++k) { u0[k] = t0[base+k]; u1[k] = t1[base+k]; u2[k] = t2[base+k]; }
#pragma unroll
    for (int j = 0; j < L; ++j) {
      float w0 = taps.k[SIG][0][L-1-j];
      float w1 = taps.k[SIG][1][L-1-j];
      float w2 = taps.k[SIG][2][L-1-j];
#pragma unroll
      for (int k = 0; k < 4; ++k) {
        hrr[k] += u2[(j+k)&3]*w0;        // Hrr = vert k2 (.) horiz k0
        hrc[k] += u1[(j+k)&3]*w1;        // Hrc = vert k1 (.) horiz k1
        hcc[k] += u0[(j+k)&3]*w2;        // Hcc = vert k0 (.) horiz k2
      }
      if (j < L-1) {
        u0[j&3] = t0[base + j + 4];
        u1[j&3] = t1[base + j + 4];
        u2[j&3] = t2[base + j + 4];
      }
    }
    float s2 = taps.s2[SIG];
#pragma unroll
    for (int k = 0; k < 4; ++k) {
      float Hrr = hrr[k]*s2, Hrc = hrc[k]*s2, Hcc = hcc[k]*s2;
      float mid  = 0.5f*(Hrr + Hcc);
      float dif  = 0.5f*(Hrr - Hcc);
      float disc = sqrtf(dif*dif + Hrc*Hrc);
      float ehi  = mid + disc;
      float elo  = mid - disc;
      bool  sm   = fabsf(ehi) <= fabsf(elo);
      float lam1 = sm ? ehi : elo;
      float lam2 = sm ? elo : ehi;
      float lam2c = fmaxf(lam2, 1e-10f);
      float q    = lam1 / lam2c;
      float rb2  = q*q;
      float ssq  = lam1*lam1 + lam2*lam2;
      float v    = expf((-rb2)/2.0f) * (1.0f - expf((-ssq)/50.0f));
      fr[k] = fmaxf(fr[k], v);
    }
  }
  __syncthreads();                       // t-arrays free for next sigma
}

__global__ __launch_bounds__(256)
void frangi_label_kernel(const float* __restrict__ img,
                         int* __restrict__ labels,
                         int* __restrict__ sizes,
                         Taps taps)
{
  __shared__ float sIn[IN_T*IN_T];
  __shared__ float t0[TILE*TSTRIDE];
  __shared__ float t1[TILE*TSTRIDE];
  __shared__ float t2[TILE*TSTRIDE];

  const int tid    = threadIdx.x;
  const int imgIdx = blockIdx.y;
  const int tIdx   = blockIdx.x;
  const int tr0    = (tIdx >> 4) * TILE;
  const int tc0    = (tIdx & 15) * TILE;
  const float* __restrict__ im = img + (size_t)imgIdx * NPIX;

  // load halo tile: reflect ('symmetric') padding, negate+scale: -(x*500)
  for (int i = tid; i < IN_T*IN_T; i += 256) {
    int r = i / IN_T;
    int c = i - r*IN_T;
    int gr = tr0 - HALO + r;
    int gc = tc0 - HALO + c;
    gr = (gr < 0) ? (-1 - gr) : ((gr >= IMG_H) ? (2*IMG_H - 1 - gr) : gr);
    gc = (gc < 0) ? (-1 - gc) : ((gc >= IMG_W) ? (2*IMG_W - 1 - gc) : gc);
    sIn[i] = -(im[gr*IMG_W + gc] * 500.0f);
  }
  __syncthreads();

  float fr[4] = {0.0f, 0.0f, 0.0f, 0.0f};
  do_sigma<0,4>(sIn, t0, t1, t2, taps, tid, fr);   // sigma 1.0
  do_sigma<1,5>(sIn, t0, t1, t2, taps, tid, fr);   // sigma 1.3
  do_sigma<2,6>(sIn, t0, t1, t2, taps, tid, fr);   // sigma 1.6
  do_sigma<3,8>(sIn, t0, t1, t2, taps, tid, fr);   // sigma 1.9
  do_sigma<4,9>(sIn, t0, t1, t2, taps, tid, fr);   // sigma 2.2

  const int r  = tid >> 3;
  const int c0 = (tid & 7) * 4;
  const int gr = tr0 + r;
  const size_t imgBase = (size_t)imgIdx * NPIX;
#pragma unroll
  for (int k = 0; k < 4; ++k) {
    int p = gr*IMG_W + tc0 + c0 + k;
    float x = im[p];
    bool m = (x >= 0.1f) && (x <= 0.5f) && (fr[k] >= 0.2f);
    labels[imgBase + p] = m ? p : -1;
    sizes[imgBase + p]  = 0;
  }
}

// ---------------------------------------------------------------------------
// 8-connected CCL: atomic union-find (min-index root), then size filter.
// ---------------------------------------------------------------------------
__device__ __forceinline__ int ldA(const int* p) {
  return __hip_atomic_load(p, __ATOMIC_RELAXED, __HIP_MEMORY_SCOPE_AGENT);
}
__device__ __forceinline__ int rootOf(const int* L, int x) {
  int pa = ldA(&L[x]);
  while (pa != x) { int g = ldA(&L[pa]); x = pa; pa = g; }
  return x;
}

__global__ __launch_bounds__(256)
void merge_kernel(int* __restrict__ labels)
{
  int gid = blockIdx.x*256 + threadIdx.x;
  int img = gid >> 18;
  int p   = gid & (NPIX - 1);
  int* L  = labels + ((size_t)img << 18);
  if (L[p] < 0) return;
  int r = p >> 9, c = p & (IMG_W - 1);
  const int dr[4] = {0,-1,-1,-1};
  const int dc[4] = {-1,-1,0,1};
#pragma unroll
  for (int k = 0; k < 4; ++k) {
    int nr = r + dr[k], nc = c + dc[k];
    if (nr < 0 || nc < 0 || nc >= IMG_W) continue;
    int q = (nr << 9) | nc;
    if (L[q] < 0) continue;
    int a = p, b = q;
    while (true) {
      a = rootOf(L, a);
      b = rootOf(L, b);
      if (a == b) break;
      int hi = a > b ? a : b;
      int lo = a < b ? a : b;
      int old = atomicCAS(&L[hi], hi, lo);     // link high root under low root
      if (old == hi) break;
      a = old; b = lo;
    }
  }
}

// compress to root + run-length-aggregated size count, fused.
__global__ __launch_bounds__(256)
void compress_count_kernel(int* __restrict__ labels, int* __restrict__ sizes)
{
  int gid = blockIdx.x*256 + threadIdx.x;
  int img = gid >> 18;
  int p   = gid & (NPIX - 1);
  int* L  = labels + ((size_t)img << 18);
  int rt  = -1;
  if (ldA(&L[p]) >= 0) {
    rt = rootOf(L, p);
    __hip_atomic_store(&L[p], rt, __ATOMIC_RELAXED, __HIP_MEMORY_SCOPE_AGENT);
  }
  int lane = threadIdx.x & 63;
  int left = __shfl_up(rt, 1);
  bool head = (lane == 0) || (left != rt);
  unsigned long long hb = __ballot(head);
  if (rt >= 0 && head) {
    unsigned long long rest = (hb >> 1) >> lane;   // heads strictly above
    int len = rest ? __ffsll((long long)rest) : (64 - lane);
    atomicAdd(&sizes[((size_t)img << 18) + rt], len);
  }
}

__global__ __launch_bounds__(256)
void output_kernel(const int* __restrict__ labels, const int* __restrict__ sizes,
                   float* __restrict__ out)
{
  int gid = blockIdx.x*256 + threadIdx.x;
  int l = labels[gid];
  float v = 0.0f;
  if (l >= 0) {
    int img = gid >> 18;
    v = (sizes[((size_t)img << 18) + l] >= MIN_SZ) ? 1.0f : 0.0f;
  }
  out[gid] = v;
}

// ---------------------------------------------------------------------------
// Host: scipy.ndimage-style Gaussian derivative kernels (truncate=4), double
// precision exactly as numpy computes them, cast to f32.
// ---------------------------------------------------------------------------
static void gauss1d(double sigma, int order, int rad, float* out)
{
  int L = 2*rad + 1;
  double phi[MAXL];
  double s = 0.0;
  for (int i = 0; i < L; ++i) {
    double x = (double)(i - rad);
    phi[i] = exp(-0.5*x*x/(sigma*sigma));
    s += phi[i];
  }
  for (int i = 0; i < L; ++i) phi[i] /= s;
  if (order == 0) {
    for (int i = 0; i < L; ++i) out[i] = (float)phi[i];
    return;
  }
  double q[3] = {1.0, 0.0, 0.0};
  for (int it = 0; it < order; ++it) {
    double nq[3] = {0.0, 0.0, 0.0};
    for (int i = 0; i <= order; ++i) {
      double v = 0.0;
      if (i+1 <= order) v += (double)(i+1) * q[i+1];
      if (i-1 >= 0)     v += (-1.0/(sigma*sigma)) * q[i-1];
      nq[i] = v;
    }
    q[0] = nq[0]; q[1] = nq[1]; q[2] = nq[2];
  }
  for (int i = 0; i < L; ++i) {
    double x = (double)(i - rad);
    double poly = q[0];
    double xp = x;
    for (int e = 1; e <= order; ++e) { poly += xp*q[e]; xp *= x; }
    out[i] = (float)(poly*phi[i]);
  }
}

extern "C" void kernel_launch(void* const* d_in, const int* in_sizes, int n_in,
                              void* d_out, int out_size, void* d_ws, size_t ws_size,
                              hipStream_t stream)
{
  (void)in_sizes; (void)n_in; (void)out_size; (void)ws_size;
  const float* img = (const float*)d_in[0];
  float* out = (float*)d_out;
  int* labels = (int*)d_ws;
  int* sizes  = labels + (size_t)NIMG * NPIX;

  Taps taps;
  memset(&taps, 0, sizeof(taps));
  for (int s = 0; s < NSIG; ++s) {
    double sigma = 1.0 + 0.3 * (double)s;      // np.arange(1.0, 2.5, 0.3)
    int rad = (int)(4.0 * sigma + 0.5);        // 4,5,6,8,9
    taps.rad[s] = rad;
    taps.s2[s]  = (float)(sigma * sigma);
    for (int o = 0; o < 3; ++o) gauss1d(sigma, o, rad, taps.k[s][o]);
  }

  dim3 gridF(NPIX / (TILE*TILE), NIMG);        // 256 tiles x 16 images
  frangi_label_kernel<<<gridF, 256, 0, stream>>>(img, labels, sizes, taps);

  int blocks = (NIMG * NPIX) / 256;            // 16384
  merge_kernel         <<<blocks, 256, 0, stream>>>(labels);
  compress_count_kernel<<<blocks, 256, 0, stream>>>(labels, sizes);
  output_kernel        <<<blocks, 256, 0, stream>>>(labels, sizes, out);
}